// Round 10
// baseline (37.935 us; speedup 1.0000x reference)
//
#include <hip/hip_runtime.h>
#include <hip/hip_bf16.h>

typedef __attribute__((ext_vector_type(4))) int i32x4;
typedef __attribute__((ext_vector_type(4))) float f32x4;

constexpr int N_PAIRS = 4096;
constexpr int TWO_N = 8192;
constexpr int D = 256;
constexpr float E2 = 7.3890560989306495f;   // exp(1/temp), temp=0.5
constexpr float QI = 317.0f;                // int8 scale
// exp(2*sim) = exp2(dot_i32 * 2*log2(e)/QI^2)
constexpr float CEXP = 2.8853900817779268f / (QI * QI);

__device__ inline float wave_reduce_sum(float v) {
#pragma unroll
  for (int m = 32; m; m >>= 1) v += __shfl_xor(v, m, 64);
  return v;
}

// zq layout (k-major, int8): 16B granule (g, row) at zq + g*131072 + row*16,
// g = k-granule 0..15, row 0..8191. Same packing for A and B so any
// k-permutation cancels in the symmetric GEMM.

// k1: normalize rows of z=[zi;zj] -> int8 zq (k-major), fp32 positive-pair
//     sims, and zero d_out for k_final's atomic accumulation.
__global__ void k_norm_pos(const float* __restrict__ zi, const float* __restrict__ zj,
                           signed char* __restrict__ zq, float* __restrict__ simpos,
                           float* __restrict__ out) {
  if (blockIdx.x == 0 && threadIdx.x == 0) out[0] = 0.0f;
  __shared__ float s_inv[4];
  int tid = threadIdx.x;
  int w = tid >> 6, l = tid & 63;
  int p = blockIdx.x * 2 + (w >> 1);   // pair index 0..4095
  int half = w & 1;                    // 0 -> zi row, 1 -> zj row
  const float* src = half ? (zj + (size_t)p * D) : (zi + (size_t)p * D);
  float4 v = reinterpret_cast<const float4*>(src)[l];
  float ss = v.x * v.x + v.y * v.y + v.z * v.z + v.w * v.w;
  ss = wave_reduce_sum(ss);
  float nrm = sqrtf(ss);
  float inv = 1.0f / fmaxf(nrm, 1e-8f);
  if (l == 0) s_inv[w] = inv;
  float sc = inv * QI;
  int row = p + half * N_PAIRS;
  int q0 = __float2int_rn(v.x * sc);
  int q1 = __float2int_rn(v.y * sc);
  int q2 = __float2int_rn(v.z * sc);
  int q3 = __float2int_rn(v.w * sc);
  q0 = q0 > 127 ? 127 : (q0 < -127 ? -127 : q0);
  q1 = q1 > 127 ? 127 : (q1 < -127 ? -127 : q1);
  q2 = q2 > 127 ? 127 : (q2 < -127 ? -127 : q2);
  q3 = q3 > 127 ? 127 : (q3 < -127 ? -127 : q3);
  unsigned int packed = (unsigned)(q0 & 255) | ((unsigned)(q1 & 255) << 8) |
                        ((unsigned)(q2 & 255) << 16) | ((unsigned)(q3 & 255) << 24);
  // lane l holds k = 4l..4l+3 -> granule g = l>>2, word w4 = l&3
  *reinterpret_cast<unsigned int*>(zq + (size_t)(l >> 2) * 131072 +
                                   (size_t)row * 16 + (l & 3) * 4) = packed;
  __syncthreads();
  if (half == 0) {  // waves 0 and 2 compute the fp32 positive-pair sims
    const float4* a = reinterpret_cast<const float4*>(zi + (size_t)p * D);
    const float4* b = reinterpret_cast<const float4*>(zj + (size_t)p * D);
    float4 x = a[l], y = b[l];
    float d = x.x * y.x + x.y * y.y + x.z * y.z + x.w * y.w;
    d = wave_reduce_sum(d);
    if (l == 0) simpos[p] = d * s_inv[w] * s_inv[w + 1];
  }
}

// k2: per row r accumulate sum_j exp(2*sim[r][j]) via INT8 MFMA.
// 8 row-tiles x 1 col-tile per wave (128 rows/wave) -> B-stream halves to
// 134 MB; 8 independent acc chains; no LDS/barriers; ping-pong B prefetch.
// 512 blocks (64 rowgrp x 8 splitgrp) x 256 thr; wave w = split sg*4+w.
__global__ __launch_bounds__(256, 2)
void k_simsum(const signed char* __restrict__ zq, float* __restrict__ partial) {
  const signed char* zt = zq;
  int tid = threadIdx.x;
  int w = tid >> 6, l = tid & 63;
  int l15 = l & 15, l4 = l >> 4;        // col/row-in-tile, k-quarter
  int rowblk = blockIdx.x >> 3, sg = blockIdx.x & 7;
  int split = sg * 4 + w;               // 0..31
  int arowbase = rowblk * 128;
  int colw = split * 256;               // wave's 256-col window

  // A fragments resident: 8 row-tiles x 4 k-steps (K=64 each); lane: row=l15
  i32x4 a[8][4];
#pragma unroll
  for (int rt = 0; rt < 8; ++rt)
#pragma unroll
    for (int ks = 0; ks < 4; ++ks)
      a[rt][ks] = *reinterpret_cast<const i32x4*>(
          zt + (size_t)(ks * 4 + l4) * 131072 + (size_t)(arowbase + rt * 16 + l15) * 16);

  f32x4 rs[8];
#pragma unroll
  for (int rt = 0; rt < 8; ++rt) rs[rt] = (f32x4)0.0f;
  const i32x4 zero4 = (i32x4)0;

  i32x4 bA[4], bB[4];  // [k-step] ping-pong; chunk = 16 cols

#define LDB(buf, ch)                                                            \
  {                                                                             \
    _Pragma("unroll") for (int ks = 0; ks < 4; ++ks)                            \
      (buf)[ks] = *reinterpret_cast<const i32x4*>(                              \
          zt + (size_t)(ks * 4 + l4) * 131072 +                                 \
          (size_t)(colw + (ch) * 16 + l15) * 16);                               \
  }
#define COMP(buf)                                                               \
  {                                                                             \
    i32x4 acc[8];                                                               \
    _Pragma("unroll") for (int ks = 0; ks < 4; ++ks)                            \
      _Pragma("unroll") for (int rt = 0; rt < 8; ++rt)                          \
        acc[rt] = __builtin_amdgcn_mfma_i32_16x16x64_i8(                        \
            a[rt][ks], (buf)[ks], ks == 0 ? zero4 : acc[rt], 0, 0, 0);          \
    _Pragma("unroll") for (int rt = 0; rt < 8; ++rt)                            \
      _Pragma("unroll") for (int q = 0; q < 4; ++q)                             \
        rs[rt][q] += __builtin_amdgcn_exp2f((float)acc[rt][q] * CEXP);          \
  }

  LDB(bA, 0);
  for (int ch2 = 0; ch2 < 8; ++ch2) {
    LDB(bB, ch2 * 2 + 1);
    COMP(bA);
    if (ch2 < 7) LDB(bA, ch2 * 2 + 2);
    COMP(bB);
  }
#undef LDB
#undef COMP

  // reduce across the 16 cols (lane&15) of each tile
#pragma unroll
  for (int m = 1; m < 16; m <<= 1) {
#pragma unroll
    for (int rt = 0; rt < 8; ++rt)
#pragma unroll
      for (int q = 0; q < 4; ++q) rs[rt][q] += __shfl_xor(rs[rt][q], m, 64);
  }
  if (l15 == 0) {
#pragma unroll
    for (int rt = 0; rt < 8; ++rt)
#pragma unroll
      for (int q = 0; q < 4; ++q) {
        // 16x16 C map (m89-verified, dtype-independent): row=(lane>>4)*4+reg
        int row = arowbase + rt * 16 + l4 * 4 + q;
        partial[(size_t)row * 32 + split] = rs[rt][q];
      }
  }
}

// k3: loss partial per block, atomically accumulated into out (zeroed by k1).
__global__ void k_final1(const float* __restrict__ partial, const float* __restrict__ simpos,
                         float* __restrict__ out) {
  __shared__ float red[2];
  int tid = threadIdx.x;
  int r = blockIdx.x * 128 + tid;
  const float4* p = reinterpret_cast<const float4*>(partial + (size_t)r * 32);
  float s = 0.0f;
#pragma unroll
  for (int i = 0; i < 8; ++i) {
    float4 q = p[i];
    s += (q.x + q.y) + (q.z + q.w);
  }
  float denom = s - E2;
  float acc = __logf(denom) - 2.0f * simpos[r & (N_PAIRS - 1)];
  acc = wave_reduce_sum(acc);
  int w = tid >> 6, l = tid & 63;
  if (l == 0) red[w] = acc;
  __syncthreads();
  if (tid == 0) atomicAdd(out, (red[0] + red[1]) * (1.0f / TWO_N));
}

extern "C" void kernel_launch(void* const* d_in, const int* in_sizes, int n_in,
                              void* d_out, int out_size, void* d_ws, size_t ws_size,
                              hipStream_t stream) {
  const float* zi = (const float*)d_in[0];
  const float* zj = (const float*)d_in[1];
  char* ws = (char*)d_ws;
  signed char* zq = (signed char*)ws;                             // 2 MB int8, k-major
  float* simpos = (float*)(ws + 2u * 1024u * 1024u);              // 16 KB
  float* partial = (float*)(ws + 2u * 1024u * 1024u + 65536u);    // 1 MB [8192][32]
  float* out = (float*)d_out;

  k_norm_pos<<<2048, 256, 0, stream>>>(zi, zj, zq, simpos, out);
  k_simsum<<<512, 256, 0, stream>>>(zq, partial);
  k_final1<<<64, 128, 0, stream>>>(partial, simpos, out);
}

// Round 11
// 36.180 us; speedup vs baseline: 1.0485x; 1.0485x over previous
//
#include <hip/hip_runtime.h>
#include <hip/hip_bf16.h>

typedef __attribute__((ext_vector_type(4))) int i32x4;
typedef __attribute__((ext_vector_type(4))) float f32x4;

constexpr int N_PAIRS = 4096;
constexpr int TWO_N = 8192;
constexpr int D = 256;
constexpr float E2 = 7.3890560989306495f;   // exp(1/temp), temp=0.5
constexpr float QI = 317.0f;                // int8 scale
// exp(2*sim) = exp2(dot_i32 * 2*log2(e)/QI^2)
constexpr float CEXP = 2.8853900817779268f / (QI * QI);

__device__ inline float wave_reduce_sum(float v) {
#pragma unroll
  for (int m = 32; m; m >>= 1) v += __shfl_xor(v, m, 64);
  return v;
}

// zq layout (k-major, int8): 16B granule (g, row) at zq + g*131072 + row*16,
// g = k-granule 0..15, row 0..8191. Same packing for A and B so any
// k-permutation cancels in the symmetric GEMM.

// k1: normalize rows of z=[zi;zj] -> int8 zq (k-major), fp32 positive-pair
//     sims, and zero d_out for k_final's atomic accumulation.
__global__ void k_norm_pos(const float* __restrict__ zi, const float* __restrict__ zj,
                           signed char* __restrict__ zq, float* __restrict__ simpos,
                           float* __restrict__ out) {
  if (blockIdx.x == 0 && threadIdx.x == 0) out[0] = 0.0f;
  __shared__ float s_inv[4];
  int tid = threadIdx.x;
  int w = tid >> 6, l = tid & 63;
  int p = blockIdx.x * 2 + (w >> 1);   // pair index 0..4095
  int half = w & 1;                    // 0 -> zi row, 1 -> zj row
  const float* src = half ? (zj + (size_t)p * D) : (zi + (size_t)p * D);
  float4 v = reinterpret_cast<const float4*>(src)[l];
  float ss = v.x * v.x + v.y * v.y + v.z * v.z + v.w * v.w;
  ss = wave_reduce_sum(ss);
  float nrm = sqrtf(ss);
  float inv = 1.0f / fmaxf(nrm, 1e-8f);
  if (l == 0) s_inv[w] = inv;
  float sc = inv * QI;
  int row = p + half * N_PAIRS;
  int q0 = __float2int_rn(v.x * sc);
  int q1 = __float2int_rn(v.y * sc);
  int q2 = __float2int_rn(v.z * sc);
  int q3 = __float2int_rn(v.w * sc);
  q0 = q0 > 127 ? 127 : (q0 < -127 ? -127 : q0);
  q1 = q1 > 127 ? 127 : (q1 < -127 ? -127 : q1);
  q2 = q2 > 127 ? 127 : (q2 < -127 ? -127 : q2);
  q3 = q3 > 127 ? 127 : (q3 < -127 ? -127 : q3);
  unsigned int packed = (unsigned)(q0 & 255) | ((unsigned)(q1 & 255) << 8) |
                        ((unsigned)(q2 & 255) << 16) | ((unsigned)(q3 & 255) << 24);
  // lane l holds k = 4l..4l+3 -> granule g = l>>2, word w4 = l&3
  *reinterpret_cast<unsigned int*>(zq + (size_t)(l >> 2) * 131072 +
                                   (size_t)row * 16 + (l & 3) * 4) = packed;
  __syncthreads();
  if (half == 0) {  // waves 0 and 2 compute the fp32 positive-pair sims
    const float4* a = reinterpret_cast<const float4*>(zi + (size_t)p * D);
    const float4* b = reinterpret_cast<const float4*>(zj + (size_t)p * D);
    float4 x = a[l], y = b[l];
    float d = x.x * y.x + x.y * y.y + x.z * y.z + x.w * y.w;
    d = wave_reduce_sum(d);
    if (l == 0) simpos[p] = d * s_inv[w] * s_inv[w + 1];
  }
}

// k2: per row r accumulate sum_j exp(2*sim[r][j]) via INT8 MFMA.
// OCCUPANCY build: wave = 64 rows x 256 cols, a[4][4]=64 VGPR, single-buffer
// B, total ~112 VGPR -> 4 waves/SIMD (launch_bounds(256,4) pins the cap).
// TLP (not ILP) hides L2 latency and the exp2 VALU tail: 4 resident waves
// per SIMD interleave their {load | MFMA | exp} phases.
// 1024 blocks (128 rowgrp x 8 splitgrp, exactly 4/CU) x 256 thr.
__global__ __launch_bounds__(256, 4)
void k_simsum(const signed char* __restrict__ zq, float* __restrict__ partial) {
  const signed char* zt = zq;
  int tid = threadIdx.x;
  int w = tid >> 6, l = tid & 63;
  int l15 = l & 15, l4 = l >> 4;        // col/row-in-tile, k-quarter
  int rowblk = blockIdx.x >> 3, sg = blockIdx.x & 7;
  int split = sg * 4 + w;               // 0..31
  int arowbase = rowblk * 64;
  int colw = split * 256;               // wave's 256-col window

  // A fragments resident: 4 row-tiles x 4 k-steps (K=64 each); lane: row=l15
  i32x4 a[4][4];
#pragma unroll
  for (int rt = 0; rt < 4; ++rt)
#pragma unroll
    for (int ks = 0; ks < 4; ++ks)
      a[rt][ks] = *reinterpret_cast<const i32x4*>(
          zt + (size_t)(ks * 4 + l4) * 131072 + (size_t)(arowbase + rt * 16 + l15) * 16);

  f32x4 rs[4];
#pragma unroll
  for (int rt = 0; rt < 4; ++rt) rs[rt] = (f32x4)0.0f;
  const i32x4 zero4 = (i32x4)0;

  for (int ch = 0; ch < 16; ++ch) {
    i32x4 b[4];
#pragma unroll
    for (int ks = 0; ks < 4; ++ks)
      b[ks] = *reinterpret_cast<const i32x4*>(
          zt + (size_t)(ks * 4 + l4) * 131072 + (size_t)(colw + ch * 16 + l15) * 16);
    i32x4 acc[4];
#pragma unroll
    for (int ks = 0; ks < 4; ++ks)
#pragma unroll
      for (int rt = 0; rt < 4; ++rt)
        acc[rt] = __builtin_amdgcn_mfma_i32_16x16x64_i8(
            a[rt][ks], b[ks], ks == 0 ? zero4 : acc[rt], 0, 0, 0);
#pragma unroll
    for (int rt = 0; rt < 4; ++rt)
#pragma unroll
      for (int q = 0; q < 4; ++q)
        rs[rt][q] += __builtin_amdgcn_exp2f((float)acc[rt][q] * CEXP);
  }

  // reduce across the 16 cols (lane&15) of each tile
#pragma unroll
  for (int m = 1; m < 16; m <<= 1) {
#pragma unroll
    for (int rt = 0; rt < 4; ++rt)
#pragma unroll
      for (int q = 0; q < 4; ++q) rs[rt][q] += __shfl_xor(rs[rt][q], m, 64);
  }
  if (l15 == 0) {
#pragma unroll
    for (int rt = 0; rt < 4; ++rt)
#pragma unroll
      for (int q = 0; q < 4; ++q) {
        // 16x16 C map (m89-verified, dtype-independent): row=(lane>>4)*4+reg
        int row = arowbase + rt * 16 + l4 * 4 + q;
        partial[(size_t)row * 32 + split] = rs[rt][q];
      }
  }
}

// k3: loss partial per block, atomically accumulated into out (zeroed by k1).
__global__ void k_final1(const float* __restrict__ partial, const float* __restrict__ simpos,
                         float* __restrict__ out) {
  __shared__ float red[2];
  int tid = threadIdx.x;
  int r = blockIdx.x * 128 + tid;
  const float4* p = reinterpret_cast<const float4*>(partial + (size_t)r * 32);
  float s = 0.0f;
#pragma unroll
  for (int i = 0; i < 8; ++i) {
    float4 q = p[i];
    s += (q.x + q.y) + (q.z + q.w);
  }
  float denom = s - E2;
  float acc = __logf(denom) - 2.0f * simpos[r & (N_PAIRS - 1)];
  acc = wave_reduce_sum(acc);
  int w = tid >> 6, l = tid & 63;
  if (l == 0) red[w] = acc;
  __syncthreads();
  if (tid == 0) atomicAdd(out, (red[0] + red[1]) * (1.0f / TWO_N));
}

extern "C" void kernel_launch(void* const* d_in, const int* in_sizes, int n_in,
                              void* d_out, int out_size, void* d_ws, size_t ws_size,
                              hipStream_t stream) {
  const float* zi = (const float*)d_in[0];
  const float* zj = (const float*)d_in[1];
  char* ws = (char*)d_ws;
  signed char* zq = (signed char*)ws;                             // 2 MB int8, k-major
  float* simpos = (float*)(ws + 2u * 1024u * 1024u);              // 16 KB
  float* partial = (float*)(ws + 2u * 1024u * 1024u + 65536u);    // 1 MB [8192][32]
  float* out = (float*)d_out;

  k_norm_pos<<<2048, 256, 0, stream>>>(zi, zj, zq, simpos, out);
  k_simsum<<<1024, 256, 0, stream>>>(zq, partial);
  k_final1<<<64, 128, 0, stream>>>(partial, simpos, out);
}